// Round 12
// baseline (190.713 us; speedup 1.0000x reference)
//
#include <hip/hip_runtime.h>
#include <hip/hip_bf16.h>

#define B_ 2
#define L_ 4096
#define DIM_ 512
#define HEADS_ 8
#define HDIM_ 64
#define KS_ 33
#define QKS_ 1024   // qk buffer row stride (Q cols 0-511, K cols 512-1023)

typedef __bf16 bf16;
typedef __bf16 bf16x4 __attribute__((ext_vector_type(4)));
typedef __bf16 bf16x8 __attribute__((ext_vector_type(8)));
typedef float f32x4 __attribute__((ext_vector_type(4)));

typedef __attribute__((address_space(3))) void lds_void;
typedef __attribute__((address_space(1))) const void glb_void;

__device__ __forceinline__ void async_cp16(const bf16* g, bf16* l)
{
    __builtin_amdgcn_global_load_lds((glb_void*)g, (lds_void*)l, 16, 0, 0);
}

// ---------------------------------------------------------------------------
// Single fused fp32->bf16 convert for all 5 inputs (R5, passing, unchanged).
// ---------------------------------------------------------------------------
__global__ __launch_bounds__(256)
void cvt_all(const float* __restrict__ x,  const float* __restrict__ wq,
             const float* __restrict__ bq, const float* __restrict__ wp,
             const float* __restrict__ bp,
             bf16* __restrict__ xb,  bf16* __restrict__ wqb,
             bf16* __restrict__ bqb, bf16* __restrict__ wpb,
             bf16* __restrict__ bpb)
{
    const int blk = blockIdx.x;
    const float* src; bf16* dst; int n, base;
    if (blk < 2048)       { src = x;  dst = xb;  n = 4194304; base = blk; }
    else if (blk < 2432)  { src = wq; dst = wqb; n = 786432;  base = blk - 2048; }
    else if (blk < 2560)  { src = wp; dst = wpb; n = 262144;  base = blk - 2432; }
    else if (blk == 2560) { src = bq; dst = bqb; n = 1536;    base = 0; }
    else                  { src = bp; dst = bpb; n = 512;     base = 0; }
    int i = base * 2048 + threadIdx.x * 8;
    if (i + 8 <= n) {
        float4 a = *(const float4*)(src + i);
        float4 b = *(const float4*)(src + i + 4);
        bf16x8 o;
        o[0] = (bf16)a.x; o[1] = (bf16)a.y; o[2] = (bf16)a.z; o[3] = (bf16)a.w;
        o[4] = (bf16)b.x; o[5] = (bf16)b.y; o[6] = (bf16)b.z; o[7] = (bf16)b.w;
        *(bf16x8*)(dst + i) = o;
    }
}

// ---------------------------------------------------------------------------
// BARRIER-FREE GEMM K-loop: MFMA fragments loaded DIRECTLY from global
// (L2-resident operands; each b128 frag load = 16 fully-consumed 64B
// cachelines — the same pattern as the attention kernel's direct Q/K loads).
// No LDS, no __syncthreads in the K-loop -> no vmcnt(0) drain points; the
// compiler pipelines 6 loads + 8 MFMAs per BK=32 step freely. This is the
// K-loop restructure the m97-plateau analysis calls for, sized to this
// problem's small-K regime. Block 256 (2x2 waves), tile 128x64, wave 64x32.
// ---------------------------------------------------------------------------
#define DGEMM_CORE(A_, W_, K_)                                                 \
    const int tid  = threadIdx.x;                                              \
    const int wave = tid >> 6;                                                 \
    const int lane = tid & 63;                                                 \
    const int wm   = (wave >> 1) * 64;                                         \
    const int wn   = (wave & 1) * 32;                                          \
    const int l16  = lane & 15;                                                \
    const int quad = lane >> 4;                                                \
    const int row0 = blockIdx.x * 128;                                         \
    const int col0 = blockIdx.y * 64;                                          \
    const bf16* Ap = (A_) + (size_t)(row0 + wm + l16) * (K_) + quad * 8;       \
    const bf16* Wp = (W_) + (size_t)(col0 + wn + l16) * (K_) + quad * 8;       \
    f32x4 acc[4][2] = {};                                                      \
    _Pragma("unroll 4")                                                        \
    for (int k = 0; k < (K_); k += 32) {                                       \
        bf16x8 af[4], bfr[2];                                                  \
        _Pragma("unroll")                                                      \
        for (int i = 0; i < 4; ++i)                                            \
            af[i] = *(const bf16x8*)(Ap + (size_t)i * 16 * (K_) + k);          \
        _Pragma("unroll")                                                      \
        for (int i = 0; i < 2; ++i)                                            \
            bfr[i] = *(const bf16x8*)(Wp + (size_t)i * 16 * (K_) + k);         \
        _Pragma("unroll")                                                      \
        for (int mi = 0; mi < 4; ++mi)                                         \
            _Pragma("unroll")                                                  \
            for (int ni = 0; ni < 2; ++ni)                                     \
                acc[mi][ni] = __builtin_amdgcn_mfma_f32_16x16x32_bf16(         \
                    af[mi], bfr[ni], acc[mi][ni], 0, 0, 0);                    \
    }

// ---------------------------------------------------------------------------
// QKV GEMM (split epilogue, R9-validated): Q,K -> qk row-major; V -> vT
// transposed (d-major), packed bf16x4 from the C-fragment's 4 row-regs.
// ---------------------------------------------------------------------------
__global__ __launch_bounds__(256)
void gemm_qkv(const bf16* __restrict__ A, const bf16* __restrict__ W,
              const bf16* __restrict__ bias,
              bf16* __restrict__ qk, bf16* __restrict__ vT)
{
    DGEMM_CORE(A, W, DIM_)

    if (col0 < 1024) {
        #pragma unroll
        for (int ni = 0; ni < 2; ++ni) {
            int n = col0 + wn + ni * 16 + l16;
            float bv = (float)bias[n];
            #pragma unroll
            for (int mi = 0; mi < 4; ++mi) {
                int mrow = row0 + wm + mi * 16 + quad * 4;
                #pragma unroll
                for (int r = 0; r < 4; ++r)
                    qk[(size_t)(mrow + r) * QKS_ + n] = (bf16)(acc[mi][ni][r] + bv);
            }
        }
    } else {
        #pragma unroll
        for (int ni = 0; ni < 2; ++ni) {
            int nf = col0 + wn + ni * 16 + l16;     // 1024..1535
            float bv = (float)bias[nf];
            int hd = nf - 1024;                     // h*64 + d
            #pragma unroll
            for (int mi = 0; mi < 4; ++mi) {
                int m = row0 + wm + mi * 16 + quad * 4;
                int b = m >> 12;
                int l = m & (L_ - 1);
                bf16x4 v4;
                #pragma unroll
                for (int r = 0; r < 4; ++r) v4[r] = (bf16)(acc[mi][ni][r] + bv);
                *(bf16x4*)(vT + ((size_t)(b * DIM_ + hd)) * L_ + l) = v4;
            }
        }
    }
}

// ---------------------------------------------------------------------------
// Proj GEMM: C[M,512] = A @ W^T + bias, fp32 out. Same barrier-free core.
// ---------------------------------------------------------------------------
__global__ __launch_bounds__(256)
void gemm_proj(const bf16* __restrict__ A, const bf16* __restrict__ W,
               const bf16* __restrict__ bias, float* __restrict__ C)
{
    DGEMM_CORE(A, W, DIM_)

    #pragma unroll
    for (int ni = 0; ni < 2; ++ni) {
        int n = col0 + wn + ni * 16 + l16;
        float bv = (float)bias[n];
        #pragma unroll
        for (int mi = 0; mi < 4; ++mi) {
            int mrow = row0 + wm + mi * 16 + quad * 4;
            #pragma unroll
            for (int r = 0; r < 4; ++r)
                C[(size_t)(mrow + r) * DIM_ + n] = acc[mi][ni][r] + bv;
        }
    }
}

// ---------------------------------------------------------------------------
// MFMA neighborhood attention, 2-wave (32-query) blocks (R10, passing).
// ---------------------------------------------------------------------------
__global__ __launch_bounds__(128)
void na1d_attn_mfma(const bf16* __restrict__ qk, const bf16* __restrict__ vT,
                    bf16* __restrict__ att)
{
    __shared__ bf16 Klds[64 * 64];
    __shared__ bf16 Plds[2][16][72];

    const int tid  = threadIdx.x;
    const int wave = tid >> 6;
    const int lane = tid & 63;
    const int l16  = lane & 15;
    const int quad = lane >> 4;

    const int xcd  = blockIdx.x & 7;
    const int s    = blockIdx.x >> 3;
    const int qtr  = s & 3;
    const int jj   = (s >> 2) & 3;
    const int h    = (s >> 4) & 7;
    const int b    = s >> 7;
    const int p    = jj * 8 + xcd;
    const int Q0   = p * 128 + qtr * 32;

    const size_t rowbase = (size_t)b * L_;

    #pragma unroll
    for (int i = 0; i < 4; ++i) {
        int ck = i * 128 + tid;
        int r  = ck >> 3;
        int pc = ck & 7;
        int lc = pc ^ (r & 7);
        int g  = Q0 - 16 + r;
        g = g < 0 ? 0 : (g > L_ - 1 ? L_ - 1 : g);
        async_cp16(qk + (rowbase + g) * QKS_ + DIM_ + h * HDIM_ + lc * 8,
                   Klds + (size_t)ck * 8);
    }

    const int q0w = Q0 + wave * 16;
    const bf16* qptr = qk + (rowbase + q0w + l16) * QKS_ + h * HDIM_ + quad * 8;
    bf16x8 qf0 = *(const bf16x8*)(qptr);
    bf16x8 qf1 = *(const bf16x8*)(qptr + 32);

    int k_base = q0w - 16;
    if (k_base > L_ - 48) k_base = L_ - 48;
    if (k_base < 0) k_base = 0;
    const int rel = k_base - (Q0 - 16);

    __syncthreads();

    f32x4 sacc[3] = {};
    #pragma unroll
    for (int t = 0; t < 3; ++t) {
        int r = rel + t * 16 + l16;
        bf16x8 kf0 = *(const bf16x8*)(Klds + r * 64 + ((quad ^ (r & 7)) * 8));
        bf16x8 kf1 = *(const bf16x8*)(Klds + r * 64 + (((4 + quad) ^ (r & 7)) * 8));
        sacc[t] = __builtin_amdgcn_mfma_f32_16x16x32_bf16(qf0, kf0, sacc[t], 0, 0, 0);
        sacc[t] = __builtin_amdgcn_mfma_f32_16x16x32_bf16(qf1, kf1, sacc[t], 0, 0, 0);
    }

    int offr[4];
    #pragma unroll
    for (int r = 0; r < 4; ++r) {
        int lq = q0w + quad * 4 + r;
        int st = lq - KS_ / 2;
        if (st < 0) st = 0;
        if (st > L_ - KS_) st = L_ - KS_;
        offr[r] = st - k_base;
    }
    float sv[3][4];
    #pragma unroll
    for (int t = 0; t < 3; ++t) {
        int j = t * 16 + l16;
        #pragma unroll
        for (int r = 0; r < 4; ++r) {
            float xv = sacc[t][r] * 0.125f;
            sv[t][r] = (j >= offr[r] && j <= offr[r] + 32) ? xv : -1e30f;
        }
    }

    float mr[4], sum[4];
    #pragma unroll
    for (int r = 0; r < 4; ++r)
        mr[r] = fmaxf(fmaxf(sv[0][r], sv[1][r]), sv[2][r]);
    #pragma unroll
    for (int o = 1; o < 16; o <<= 1)
        #pragma unroll
        for (int r = 0; r < 4; ++r)
            mr[r] = fmaxf(mr[r], __shfl_xor(mr[r], o, 64));
    #pragma unroll
    for (int t = 0; t < 3; ++t)
        #pragma unroll
        for (int r = 0; r < 4; ++r)
            sv[t][r] = __expf(sv[t][r] - mr[r]);
    #pragma unroll
    for (int r = 0; r < 4; ++r)
        sum[r] = sv[0][r] + sv[1][r] + sv[2][r];
    #pragma unroll
    for (int o = 1; o < 16; o <<= 1)
        #pragma unroll
        for (int r = 0; r < 4; ++r)
            sum[r] += __shfl_xor(sum[r], o, 64);
    #pragma unroll
    for (int r = 0; r < 4; ++r) {
        float inv = 1.0f / sum[r];
        #pragma unroll
        for (int t = 0; t < 3; ++t) sv[t][r] *= inv;
    }

    bf16* P = &Plds[wave][0][0];
    {
        int rr = lane >> 2;
        int c0 = 48 + (lane & 3) * 4;
        *(bf16x4*)(&P[rr * 72 + c0]) = (bf16x4){(bf16)0.f, (bf16)0.f, (bf16)0.f, (bf16)0.f};
    }
    #pragma unroll
    for (int t = 0; t < 3; ++t)
        #pragma unroll
        for (int r = 0; r < 4; ++r)
            P[(quad * 4 + r) * 72 + t * 16 + l16] = (bf16)sv[t][r];
    __syncthreads();

    bf16x8 pf0 = *(const bf16x8*)(&P[l16 * 72 + quad * 8]);
    bf16x8 pf1 = *(const bf16x8*)(&P[l16 * 72 + 32 + quad * 8]);

    const bf16* vbase = vT + (size_t)(b * DIM_ + h * HDIM_) * L_;
    int c1 = k_base + quad * 8;
    int c2 = k_base + 32 + quad * 8;
    if (c2 > L_ - 8) c2 = L_ - 8;
    f32x4 o[4] = {};
    #pragma unroll
    for (int t = 0; t < 4; ++t) {
        const bf16* vrow = vbase + (size_t)(t * 16 + l16) * L_;
        bf16x8 vf0 = *(const bf16x8*)(vrow + c1);
        bf16x8 vf1 = *(const bf16x8*)(vrow + c2);
        o[t] = __builtin_amdgcn_mfma_f32_16x16x32_bf16(pf0, vf0, o[t], 0, 0, 0);
        o[t] = __builtin_amdgcn_mfma_f32_16x16x32_bf16(pf1, vf1, o[t], 0, 0, 0);
    }

    bf16* orow = att + (rowbase + q0w) * DIM_ + h * HDIM_;
    #pragma unroll
    for (int t = 0; t < 4; ++t)
        #pragma unroll
        for (int r = 0; r < 4; ++r)
            orow[(size_t)(quad * 4 + r) * DIM_ + t * 16 + l16] = (bf16)o[t][r];
}

extern "C" void kernel_launch(void* const* d_in, const int* in_sizes, int n_in,
                              void* d_out, int out_size, void* d_ws, size_t ws_size,
                              hipStream_t stream) {
    const int n_x  = B_ * L_ * DIM_;       // 4194304
    const int n_wq = 3 * DIM_ * DIM_;      // 786432
    const int n_bq = 3 * DIM_;             // 1536
    const int n_wp = DIM_ * DIM_;          // 262144
    const int n_bp = DIM_;                 // 512

    char* ws = (char*)d_ws;
    bf16* xb  = (bf16*)ws;
    bf16* wqb = xb  + n_x;
    bf16* bqb = wqb + n_wq;
    bf16* wpb = bqb + n_bq;
    bf16* bpb = wpb + n_wp;
    bf16* qk  = bpb + n_bp;                          // 8192 x 1024
    bf16* vT  = qk  + (size_t)8192 * 1024;           // (b, h*d, l)
    bf16* att = vT  + (size_t)B_ * DIM_ * L_;        // 8192 x 512

    float* out = (float*)d_out;
    const int M = B_ * L_;  // 8192

    cvt_all<<<2562, 256, 0, stream>>>(
        (const float*)d_in[0], (const float*)d_in[1], (const float*)d_in[2],
        (const float*)d_in[3], (const float*)d_in[4],
        xb, wqb, bqb, wpb, bpb);

    gemm_qkv<<<dim3(M / 128, (3 * DIM_) / 64), 256, 0, stream>>>(
        xb, wqb, bqb, qk, vT);

    na1d_attn_mfma<<<dim3((B_ * HEADS_ * L_) / 32), 128, 0, stream>>>(qk, vT, att);

    gemm_proj<<<dim3(M / 128, DIM_ / 64), 256, 0, stream>>>(
        att, wpb, bpb, out);
}

// Round 13
// 122.614 us; speedup vs baseline: 1.5554x; 1.5554x over previous
//
#include <hip/hip_runtime.h>
#include <hip/hip_bf16.h>

#define B_ 2
#define L_ 4096
#define DIM_ 512
#define HEADS_ 8
#define HDIM_ 64
#define KS_ 33
#define QKS_ 1024   // qk buffer row stride (Q cols 0-511, K cols 512-1023)

typedef __bf16 bf16;
typedef __bf16 bf16x4 __attribute__((ext_vector_type(4)));
typedef __bf16 bf16x8 __attribute__((ext_vector_type(8)));
typedef float f32x4 __attribute__((ext_vector_type(4)));

typedef __attribute__((address_space(3))) void lds_void;
typedef __attribute__((address_space(1))) const void glb_void;

__device__ __forceinline__ void async_cp16(const bf16* g, bf16* l)
{
    __builtin_amdgcn_global_load_lds((glb_void*)g, (lds_void*)l, 16, 0, 0);
}

// ---------------------------------------------------------------------------
// fp32->bf16 convert for WEIGHTS/BIASES only (x is converted in-flight by
// gemm_qkv's A-staging now). wq 384 blks | wp 128 | bq 1 | bp 1.
// ---------------------------------------------------------------------------
__global__ __launch_bounds__(256)
void cvt_w(const float* __restrict__ wq, const float* __restrict__ bq,
           const float* __restrict__ wp, const float* __restrict__ bp,
           bf16* __restrict__ wqb, bf16* __restrict__ bqb,
           bf16* __restrict__ wpb, bf16* __restrict__ bpb)
{
    const int blk = blockIdx.x;
    const float* src; bf16* dst; int n, base;
    if (blk < 384)        { src = wq; dst = wqb; n = 786432; base = blk; }
    else if (blk < 512)   { src = wp; dst = wpb; n = 262144; base = blk - 384; }
    else if (blk == 512)  { src = bq; dst = bqb; n = 1536;   base = 0; }
    else                  { src = bp; dst = bpb; n = 512;    base = 0; }
    int i = base * 2048 + threadIdx.x * 8;
    if (i + 8 <= n) {
        float4 a = *(const float4*)(src + i);
        float4 b = *(const float4*)(src + i + 4);
        bf16x8 o;
        o[0] = (bf16)a.x; o[1] = (bf16)a.y; o[2] = (bf16)a.z; o[3] = (bf16)a.w;
        o[4] = (bf16)b.x; o[5] = (bf16)b.y; o[6] = (bf16)b.z; o[7] = (bf16)b.w;
        *(bf16x8*)(dst + i) = o;
    }
}

// ---------------------------------------------------------------------------
// QKV GEMM (R8/R9-validated structure: tile 128x64, BK=64, 6 blocks/CU).
// A is staged DIRECTLY FROM FP32 x: float4 x2 load -> cvt -> ds_write_b128
// into the same XOR-swizzled physical layout (fragment reads unchanged,
// arithmetic bit-identical). W staged via async global_load_lds (bf16).
// Epilogue split: Q,K -> qk row-major; V -> vT[b][h][d][l] transposed.
// ---------------------------------------------------------------------------
__global__ __launch_bounds__(256)
void gemm_qkv(const float* __restrict__ X, const bf16* __restrict__ W,
              const bf16* __restrict__ bias,
              bf16* __restrict__ qk, bf16* __restrict__ vT)
{
    __shared__ bf16 As[128][64];
    __shared__ bf16 Bs[64][64];

    const int tid  = threadIdx.x;
    const int wave = tid >> 6;
    const int lane = tid & 63;
    const int wm   = (wave >> 1) * 64;
    const int wn   = (wave & 1) * 32;
    const int l16  = lane & 15;
    const int quad = lane >> 4;

    const int row0 = blockIdx.x * 128;
    const int col0 = blockIdx.y * 64;
    const int K    = DIM_;

    f32x4 acc[4][2] = {};

    for (int k0 = 0; k0 < K; k0 += 64) {
        // W tile: 512 chunks async bf16
        #pragma unroll
        for (int it = 0; it < 2; ++it) {
            int g = it * 256 + tid;
            int r = g >> 3, pc = g & 7, lc = pc ^ (r & 7);
            async_cp16(&W[(size_t)(col0 + r) * K + k0 + lc * 8], &Bs[r][pc * 8]);
        }
        // A tile: 1024 chunks, fp32 load + cvt + ds_write (fused conversion)
        #pragma unroll
        for (int it = 0; it < 4; ++it) {
            int f = it * 256 + tid;
            int r = f >> 3, pc = f & 7, lc = pc ^ (r & 7);
            const float* src = X + (size_t)(row0 + r) * K + k0 + lc * 8;
            float4 a = *(const float4*)src;
            float4 b = *(const float4*)(src + 4);
            bf16x8 o;
            o[0] = (bf16)a.x; o[1] = (bf16)a.y; o[2] = (bf16)a.z; o[3] = (bf16)a.w;
            o[4] = (bf16)b.x; o[5] = (bf16)b.y; o[6] = (bf16)b.z; o[7] = (bf16)b.w;
            *(bf16x8*)(&As[r][pc * 8]) = o;
        }
        __syncthreads();

        #pragma unroll
        for (int ks = 0; ks < 2; ++ks) {
            bf16x8 af[4], bfr[2];
            #pragma unroll
            for (int i = 0; i < 4; ++i) {
                int ra = wm + i * 16 + l16;
                af[i] = *(const bf16x8*)(&As[ra][((ks * 4 + quad) ^ (ra & 7)) * 8]);
            }
            #pragma unroll
            for (int i = 0; i < 2; ++i) {
                int rb = wn + i * 16 + l16;
                bfr[i] = *(const bf16x8*)(&Bs[rb][((ks * 4 + quad) ^ (rb & 7)) * 8]);
            }
            #pragma unroll
            for (int mi = 0; mi < 4; ++mi)
                #pragma unroll
                for (int ni = 0; ni < 2; ++ni)
                    acc[mi][ni] = __builtin_amdgcn_mfma_f32_16x16x32_bf16(
                        af[mi], bfr[ni], acc[mi][ni], 0, 0, 0);
        }
        __syncthreads();
    }

    if (col0 < 1024) {
        #pragma unroll
        for (int ni = 0; ni < 2; ++ni) {
            int n = col0 + wn + ni * 16 + l16;
            float bv = (float)bias[n];
            #pragma unroll
            for (int mi = 0; mi < 4; ++mi) {
                int mrow = row0 + wm + mi * 16 + quad * 4;
                #pragma unroll
                for (int r = 0; r < 4; ++r)
                    qk[(size_t)(mrow + r) * QKS_ + n] = (bf16)(acc[mi][ni][r] + bv);
            }
        }
    } else {
        #pragma unroll
        for (int ni = 0; ni < 2; ++ni) {
            int nf = col0 + wn + ni * 16 + l16;     // 1024..1535
            float bv = (float)bias[nf];
            int hd = nf - 1024;                     // h*64 + d
            #pragma unroll
            for (int mi = 0; mi < 4; ++mi) {
                int m = row0 + wm + mi * 16 + quad * 4;
                int b = m >> 12;
                int l = m & (L_ - 1);
                bf16x4 v4;
                #pragma unroll
                for (int r = 0; r < 4; ++r) v4[r] = (bf16)(acc[mi][ni][r] + bv);
                *(bf16x4*)(vT + ((size_t)(b * DIM_ + hd)) * L_ + l) = v4;
            }
        }
    }
}

// ---------------------------------------------------------------------------
// Proj GEMM (R8-validated, 118.0 config): tile 128x64, BK=64, async XOR
// staging, fp32 out.
// ---------------------------------------------------------------------------
__global__ __launch_bounds__(256)
void gemm_proj(const bf16* __restrict__ A, const bf16* __restrict__ W,
               const bf16* __restrict__ bias, float* __restrict__ C)
{
    __shared__ bf16 As[128][64];
    __shared__ bf16 Bs[64][64];

    const int tid  = threadIdx.x;
    const int wave = tid >> 6;
    const int lane = tid & 63;
    const int wm   = (wave >> 1) * 64;
    const int wn   = (wave & 1) * 32;
    const int l16  = lane & 15;
    const int quad = lane >> 4;

    const int row0 = blockIdx.x * 128;
    const int col0 = blockIdx.y * 64;
    const int K    = DIM_;

    f32x4 acc[4][2] = {};

    for (int k0 = 0; k0 < K; k0 += 64) {
        #pragma unroll
        for (int it = 0; it < 6; ++it) {
            int f = it * 256 + tid;
            if (f < 1024) {
                int r = f >> 3, pc = f & 7, lc = pc ^ (r & 7);
                async_cp16(&A[(size_t)(row0 + r) * K + k0 + lc * 8], &As[r][pc * 8]);
            } else {
                int g = f - 1024;
                int r = g >> 3, pc = g & 7, lc = pc ^ (r & 7);
                async_cp16(&W[(size_t)(col0 + r) * K + k0 + lc * 8], &Bs[r][pc * 8]);
            }
        }
        __syncthreads();

        #pragma unroll
        for (int ks = 0; ks < 2; ++ks) {
            bf16x8 af[4], bfr[2];
            #pragma unroll
            for (int i = 0; i < 4; ++i) {
                int ra = wm + i * 16 + l16;
                af[i] = *(const bf16x8*)(&As[ra][((ks * 4 + quad) ^ (ra & 7)) * 8]);
            }
            #pragma unroll
            for (int i = 0; i < 2; ++i) {
                int rb = wn + i * 16 + l16;
                bfr[i] = *(const bf16x8*)(&Bs[rb][((ks * 4 + quad) ^ (rb & 7)) * 8]);
            }
            #pragma unroll
            for (int mi = 0; mi < 4; ++mi)
                #pragma unroll
                for (int ni = 0; ni < 2; ++ni)
                    acc[mi][ni] = __builtin_amdgcn_mfma_f32_16x16x32_bf16(
                        af[mi], bfr[ni], acc[mi][ni], 0, 0, 0);
        }
        __syncthreads();
    }

    #pragma unroll
    for (int ni = 0; ni < 2; ++ni) {
        int n = col0 + wn + ni * 16 + l16;
        float bv = (float)bias[n];
        #pragma unroll
        for (int mi = 0; mi < 4; ++mi) {
            int mrow = row0 + wm + mi * 16 + quad * 4;
            #pragma unroll
            for (int r = 0; r < 4; ++r)
                C[(size_t)(mrow + r) * DIM_ + n] = acc[mi][ni][r] + bv;
        }
    }
}

// ---------------------------------------------------------------------------
// MFMA neighborhood attention (R8-validated 118.0 config): 4-wave blocks,
// 64 queries; K staged via global_load_lds XOR-swizzled; V direct from vT.
// ---------------------------------------------------------------------------
__global__ __launch_bounds__(256)
void na1d_attn_mfma(const bf16* __restrict__ qk, const bf16* __restrict__ vT,
                    bf16* __restrict__ att)
{
    __shared__ bf16 Klds[96 * 64];
    __shared__ bf16 Plds[4][16][72];

    const int tid  = threadIdx.x;
    const int wave = tid >> 6;
    const int lane = tid & 63;
    const int l16  = lane & 15;
    const int quad = lane >> 4;

    const int xcd  = blockIdx.x & 7;
    const int s    = blockIdx.x >> 3;
    const int jj   = s & 3;
    const int half = (s >> 2) & 1;
    const int h    = (s >> 3) & 7;
    const int b    = s >> 6;
    const int p    = jj * 8 + xcd;
    const int Q0   = p * 128 + half * 64;

    const size_t rowbase = (size_t)b * L_;

    #pragma unroll
    for (int i = 0; i < 3; ++i) {
        int ck = i * 256 + tid;
        int r  = ck >> 3;
        int pc = ck & 7;
        int lc = pc ^ (r & 7);
        int g  = Q0 - 16 + r;
        g = g < 0 ? 0 : (g > L_ - 1 ? L_ - 1 : g);
        async_cp16(qk + (rowbase + g) * QKS_ + DIM_ + h * HDIM_ + lc * 8,
                   Klds + (size_t)ck * 8);
    }

    const int q0w = Q0 + wave * 16;
    const bf16* qptr = qk + (rowbase + q0w + l16) * QKS_ + h * HDIM_ + quad * 8;
    bf16x8 qf0 = *(const bf16x8*)(qptr);
    bf16x8 qf1 = *(const bf16x8*)(qptr + 32);

    int k_base = q0w - 16;
    if (k_base > L_ - 48) k_base = L_ - 48;
    if (k_base < 0) k_base = 0;
    const int rel = k_base - (Q0 - 16);

    __syncthreads();

    f32x4 sacc[3] = {};
    #pragma unroll
    for (int t = 0; t < 3; ++t) {
        int r = rel + t * 16 + l16;
        bf16x8 kf0 = *(const bf16x8*)(Klds + r * 64 + ((quad ^ (r & 7)) * 8));
        bf16x8 kf1 = *(const bf16x8*)(Klds + r * 64 + (((4 + quad) ^ (r & 7)) * 8));
        sacc[t] = __builtin_amdgcn_mfma_f32_16x16x32_bf16(qf0, kf0, sacc[t], 0, 0, 0);
        sacc[t] = __builtin_amdgcn_mfma_f32_16x16x32_bf16(qf1, kf1, sacc[t], 0, 0, 0);
    }

    int offr[4];
    #pragma unroll
    for (int r = 0; r < 4; ++r) {
        int lq = q0w + quad * 4 + r;
        int st = lq - KS_ / 2;
        if (st < 0) st = 0;
        if (st > L_ - KS_) st = L_ - KS_;
        offr[r] = st - k_base;
    }
    float sv[3][4];
    #pragma unroll
    for (int t = 0; t < 3; ++t) {
        int j = t * 16 + l16;
        #pragma unroll
        for (int r = 0; r < 4; ++r) {
            float xv = sacc[t][r] * 0.125f;
            sv[t][r] = (j >= offr[r] && j <= offr[r] + 32) ? xv : -1e30f;
        }
    }

    float mr[4], sum[4];
    #pragma unroll
    for (int r = 0; r < 4; ++r)
        mr[r] = fmaxf(fmaxf(sv[0][r], sv[1][r]), sv[2][r]);
    #pragma unroll
    for (int o = 1; o < 16; o <<= 1)
        #pragma unroll
        for (int r = 0; r < 4; ++r)
            mr[r] = fmaxf(mr[r], __shfl_xor(mr[r], o, 64));
    #pragma unroll
    for (int t = 0; t < 3; ++t)
        #pragma unroll
        for (int r = 0; r < 4; ++r)
            sv[t][r] = __expf(sv[t][r] - mr[r]);
    #pragma unroll
    for (int r = 0; r < 4; ++r)
        sum[r] = sv[0][r] + sv[1][r] + sv[2][r];
    #pragma unroll
    for (int o = 1; o < 16; o <<= 1)
        #pragma unroll
        for (int r = 0; r < 4; ++r)
            sum[r] += __shfl_xor(sum[r], o, 64);
    #pragma unroll
    for (int r = 0; r < 4; ++r) {
        float inv = 1.0f / sum[r];
        #pragma unroll
        for (int t = 0; t < 3; ++t) sv[t][r] *= inv;
    }

    bf16* P = &Plds[wave][0][0];
    {
        int rr = lane >> 2;
        int c0 = 48 + (lane & 3) * 4;
        *(bf16x4*)(&P[rr * 72 + c0]) = (bf16x4){(bf16)0.f, (bf16)0.f, (bf16)0.f, (bf16)0.f};
    }
    #pragma unroll
    for (int t = 0; t < 3; ++t)
        #pragma unroll
        for (int r = 0; r < 4; ++r)
            P[(quad * 4 + r) * 72 + t * 16 + l16] = (bf16)sv[t][r];
    __syncthreads();

    bf16x8 pf0 = *(const bf16x8*)(&P[l16 * 72 + quad * 8]);
    bf16x8 pf1 = *(const bf16x8*)(&P[l16 * 72 + 32 + quad * 8]);

    const bf16* vbase = vT + (size_t)(b * DIM_ + h * HDIM_) * L_;
    int c1 = k_base + quad * 8;
    int c2 = k_base + 32 + quad * 8;
    if (c2 > L_ - 8) c2 = L_ - 8;
    f32x4 o[4] = {};
    #pragma unroll
    for (int t = 0; t < 4; ++t) {
        const bf16* vrow = vbase + (size_t)(t * 16 + l16) * L_;
        bf16x8 vf0 = *(const bf16x8*)(vrow + c1);
        bf16x8 vf1 = *(const bf16x8*)(vrow + c2);
        o[t] = __builtin_amdgcn_mfma_f32_16x16x32_bf16(pf0, vf0, o[t], 0, 0, 0);
        o[t] = __builtin_amdgcn_mfma_f32_16x16x32_bf16(pf1, vf1, o[t], 0, 0, 0);
    }

    bf16* orow = att + (rowbase + q0w) * DIM_ + h * HDIM_;
    #pragma unroll
    for (int t = 0; t < 4; ++t)
        #pragma unroll
        for (int r = 0; r < 4; ++r)
            orow[(size_t)(quad * 4 + r) * DIM_ + t * 16 + l16] = (bf16)o[t][r];
}

extern "C" void kernel_launch(void* const* d_in, const int* in_sizes, int n_in,
                              void* d_out, int out_size, void* d_ws, size_t ws_size,
                              hipStream_t stream) {
    const int n_wq = 3 * DIM_ * DIM_;      // 786432
    const int n_bq = 3 * DIM_;             // 1536
    const int n_wp = DIM_ * DIM_;          // 262144
    const int n_bp = DIM_;                 // 512

    char* ws = (char*)d_ws;
    bf16* wqb = (bf16*)ws;
    bf16* bqb = wqb + n_wq;
    bf16* wpb = bqb + n_bq;
    bf16* bpb = wpb + n_wp;
    bf16* qk  = bpb + n_bp;                          // 8192 x 1024
    bf16* vT  = qk  + (size_t)8192 * 1024;           // (b, h*d, l)
    bf16* att = vT  + (size_t)B_ * DIM_ * L_;        // 8192 x 512

    float* out = (float*)d_out;
    const int M = B_ * L_;  // 8192

    cvt_w<<<514, 256, 0, stream>>>(
        (const float*)d_in[1], (const float*)d_in[2],
        (const float*)d_in[3], (const float*)d_in[4],
        wqb, bqb, wpb, bpb);

    gemm_qkv<<<dim3(M / 128, (3 * DIM_) / 64), 256, 0, stream>>>(
        (const float*)d_in[0], wqb, bqb, qk, vT);

    na1d_attn_mfma<<<dim3((B_ * HEADS_ * L_) / 64), 256, 0, stream>>>(qk, vT, att);

    gemm_proj<<<dim3(M / 128, DIM_ / 64), 256, 0, stream>>>(
        att, wpb, bpb, out);
}

// Round 14
// 118.662 us; speedup vs baseline: 1.6072x; 1.0333x over previous
//
#include <hip/hip_runtime.h>
#include <hip/hip_bf16.h>

#define B_ 2
#define L_ 4096
#define DIM_ 512
#define HEADS_ 8
#define HDIM_ 64
#define KS_ 33
#define QKS_ 1024   // qk buffer row stride (Q cols 0-511, K cols 512-1023)

typedef __bf16 bf16;
typedef __bf16 bf16x4 __attribute__((ext_vector_type(4)));
typedef __bf16 bf16x8 __attribute__((ext_vector_type(8)));
typedef float f32x4 __attribute__((ext_vector_type(4)));

typedef __attribute__((address_space(3))) void lds_void;
typedef __attribute__((address_space(1))) const void glb_void;

__device__ __forceinline__ void async_cp16(const bf16* g, bf16* l)
{
    __builtin_amdgcn_global_load_lds((glb_void*)g, (lds_void*)l, 16, 0, 0);
}

// ---------------------------------------------------------------------------
// Single fused fp32->bf16 convert for all 5 inputs (R5-validated).
// ---------------------------------------------------------------------------
__global__ __launch_bounds__(256)
void cvt_all(const float* __restrict__ x,  const float* __restrict__ wq,
             const float* __restrict__ bq, const float* __restrict__ wp,
             const float* __restrict__ bp,
             bf16* __restrict__ xb,  bf16* __restrict__ wqb,
             bf16* __restrict__ bqb, bf16* __restrict__ wpb,
             bf16* __restrict__ bpb)
{
    const int blk = blockIdx.x;
    const float* src; bf16* dst; int n, base;
    if (blk < 2048)       { src = x;  dst = xb;  n = 4194304; base = blk; }
    else if (blk < 2432)  { src = wq; dst = wqb; n = 786432;  base = blk - 2048; }
    else if (blk < 2560)  { src = wp; dst = wpb; n = 262144;  base = blk - 2432; }
    else if (blk == 2560) { src = bq; dst = bqb; n = 1536;    base = 0; }
    else                  { src = bp; dst = bpb; n = 512;     base = 0; }
    int i = base * 2048 + threadIdx.x * 8;
    if (i + 8 <= n) {
        float4 a = *(const float4*)(src + i);
        float4 b = *(const float4*)(src + i + 4);
        bf16x8 o;
        o[0] = (bf16)a.x; o[1] = (bf16)a.y; o[2] = (bf16)a.z; o[3] = (bf16)a.w;
        o[4] = (bf16)b.x; o[5] = (bf16)b.y; o[6] = (bf16)b.z; o[7] = (bf16)b.w;
        *(bf16x8*)(dst + i) = o;
    }
}

// ---------------------------------------------------------------------------
// QKV GEMM (R9-measured-best config, 118.0 us): tile 128(M) x 64(N), BK=64,
// 256 threads, per-wave 64x32 (acc[4][2]), 6 blocks/CU. Staging via
// global_load_lds width=16 + XOR swizzle (A 1024 + B 512 chunks, 6/thread).
// Epilogue split: Q,K -> qk row-major; V -> vT[b][h][d][l] transposed
// (d-major, packed bf16x4 from the C-fragment's 4 row-regs).
// ---------------------------------------------------------------------------
__global__ __launch_bounds__(256)
void gemm_qkv(const bf16* __restrict__ A, const bf16* __restrict__ W,
              const bf16* __restrict__ bias,
              bf16* __restrict__ qk, bf16* __restrict__ vT)
{
    __shared__ bf16 As[128][64];
    __shared__ bf16 Bs[64][64];

    const int tid  = threadIdx.x;
    const int wave = tid >> 6;
    const int lane = tid & 63;
    const int wm   = (wave >> 1) * 64;
    const int wn   = (wave & 1) * 32;
    const int l16  = lane & 15;
    const int quad = lane >> 4;

    const int row0 = blockIdx.x * 128;
    const int col0 = blockIdx.y * 64;
    const int K    = DIM_;

    f32x4 acc[4][2] = {};

    for (int k0 = 0; k0 < K; k0 += 64) {
        #pragma unroll
        for (int it = 0; it < 6; ++it) {
            int f = it * 256 + tid;
            if (f < 1024) {
                int r = f >> 3, pc = f & 7, lc = pc ^ (r & 7);
                async_cp16(&A[(size_t)(row0 + r) * K + k0 + lc * 8], &As[r][pc * 8]);
            } else {
                int g = f - 1024;
                int r = g >> 3, pc = g & 7, lc = pc ^ (r & 7);
                async_cp16(&W[(size_t)(col0 + r) * K + k0 + lc * 8], &Bs[r][pc * 8]);
            }
        }
        __syncthreads();

        #pragma unroll
        for (int ks = 0; ks < 2; ++ks) {
            bf16x8 af[4], bfr[2];
            #pragma unroll
            for (int i = 0; i < 4; ++i) {
                int ra = wm + i * 16 + l16;
                af[i] = *(const bf16x8*)(&As[ra][((ks * 4 + quad) ^ (ra & 7)) * 8]);
            }
            #pragma unroll
            for (int i = 0; i < 2; ++i) {
                int rb = wn + i * 16 + l16;
                bfr[i] = *(const bf16x8*)(&Bs[rb][((ks * 4 + quad) ^ (rb & 7)) * 8]);
            }
            #pragma unroll
            for (int mi = 0; mi < 4; ++mi)
                #pragma unroll
                for (int ni = 0; ni < 2; ++ni)
                    acc[mi][ni] = __builtin_amdgcn_mfma_f32_16x16x32_bf16(
                        af[mi], bfr[ni], acc[mi][ni], 0, 0, 0);
        }
        __syncthreads();
    }

    if (col0 < 1024) {
        #pragma unroll
        for (int ni = 0; ni < 2; ++ni) {
            int n = col0 + wn + ni * 16 + l16;
            float bv = (float)bias[n];
            #pragma unroll
            for (int mi = 0; mi < 4; ++mi) {
                int mrow = row0 + wm + mi * 16 + quad * 4;
                #pragma unroll
                for (int r = 0; r < 4; ++r)
                    qk[(size_t)(mrow + r) * QKS_ + n] = (bf16)(acc[mi][ni][r] + bv);
            }
        }
    } else {
        #pragma unroll
        for (int ni = 0; ni < 2; ++ni) {
            int nf = col0 + wn + ni * 16 + l16;     // 1024..1535
            float bv = (float)bias[nf];
            int hd = nf - 1024;                     // h*64 + d
            #pragma unroll
            for (int mi = 0; mi < 4; ++mi) {
                int m = row0 + wm + mi * 16 + quad * 4;
                int b = m >> 12;
                int l = m & (L_ - 1);
                bf16x4 v4;
                #pragma unroll
                for (int r = 0; r < 4; ++r) v4[r] = (bf16)(acc[mi][ni][r] + bv);
                *(bf16x4*)(vT + ((size_t)(b * DIM_ + hd)) * L_ + l) = v4;
            }
        }
    }
}

// ---------------------------------------------------------------------------
// Proj GEMM (R9-measured-best config): tile 128x64, BK=64, async XOR
// staging, fp32 out.
// ---------------------------------------------------------------------------
__global__ __launch_bounds__(256)
void gemm_proj(const bf16* __restrict__ A, const bf16* __restrict__ W,
               const bf16* __restrict__ bias, float* __restrict__ C)
{
    __shared__ bf16 As[128][64];
    __shared__ bf16 Bs[64][64];

    const int tid  = threadIdx.x;
    const int wave = tid >> 6;
    const int lane = tid & 63;
    const int wm   = (wave >> 1) * 64;
    const int wn   = (wave & 1) * 32;
    const int l16  = lane & 15;
    const int quad = lane >> 4;

    const int row0 = blockIdx.x * 128;
    const int col0 = blockIdx.y * 64;
    const int K    = DIM_;

    f32x4 acc[4][2] = {};

    for (int k0 = 0; k0 < K; k0 += 64) {
        #pragma unroll
        for (int it = 0; it < 6; ++it) {
            int f = it * 256 + tid;
            if (f < 1024) {
                int r = f >> 3, pc = f & 7, lc = pc ^ (r & 7);
                async_cp16(&A[(size_t)(row0 + r) * K + k0 + lc * 8], &As[r][pc * 8]);
            } else {
                int g = f - 1024;
                int r = g >> 3, pc = g & 7, lc = pc ^ (r & 7);
                async_cp16(&W[(size_t)(col0 + r) * K + k0 + lc * 8], &Bs[r][pc * 8]);
            }
        }
        __syncthreads();

        #pragma unroll
        for (int ks = 0; ks < 2; ++ks) {
            bf16x8 af[4], bfr[2];
            #pragma unroll
            for (int i = 0; i < 4; ++i) {
                int ra = wm + i * 16 + l16;
                af[i] = *(const bf16x8*)(&As[ra][((ks * 4 + quad) ^ (ra & 7)) * 8]);
            }
            #pragma unroll
            for (int i = 0; i < 2; ++i) {
                int rb = wn + i * 16 + l16;
                bfr[i] = *(const bf16x8*)(&Bs[rb][((ks * 4 + quad) ^ (rb & 7)) * 8]);
            }
            #pragma unroll
            for (int mi = 0; mi < 4; ++mi)
                #pragma unroll
                for (int ni = 0; ni < 2; ++ni)
                    acc[mi][ni] = __builtin_amdgcn_mfma_f32_16x16x32_bf16(
                        af[mi], bfr[ni], acc[mi][ni], 0, 0, 0);
        }
        __syncthreads();
    }

    #pragma unroll
    for (int ni = 0; ni < 2; ++ni) {
        int n = col0 + wn + ni * 16 + l16;
        float bv = (float)bias[n];
        #pragma unroll
        for (int mi = 0; mi < 4; ++mi) {
            int mrow = row0 + wm + mi * 16 + quad * 4;
            #pragma unroll
            for (int r = 0; r < 4; ++r)
                C[(size_t)(mrow + r) * DIM_ + n] = acc[mi][ni][r] + bv;
        }
    }
}

// ---------------------------------------------------------------------------
// MFMA neighborhood attention (R9-measured-best config): 4-wave blocks,
// 64 queries; K staged via global_load_lds XOR-swizzled; V direct from vT
// (d-major). XCD decode keeps query-panel p on XCD p%8 (matches writers).
// ---------------------------------------------------------------------------
__global__ __launch_bounds__(256)
void na1d_attn_mfma(const bf16* __restrict__ qk, const bf16* __restrict__ vT,
                    bf16* __restrict__ att)
{
    __shared__ bf16 Klds[96 * 64];
    __shared__ bf16 Plds[4][16][72];

    const int tid  = threadIdx.x;
    const int wave = tid >> 6;
    const int lane = tid & 63;
    const int l16  = lane & 15;
    const int quad = lane >> 4;

    const int xcd  = blockIdx.x & 7;
    const int s    = blockIdx.x >> 3;
    const int jj   = s & 3;
    const int half = (s >> 2) & 1;
    const int h    = (s >> 3) & 7;
    const int b    = s >> 6;
    const int p    = jj * 8 + xcd;
    const int Q0   = p * 128 + half * 64;

    const size_t rowbase = (size_t)b * L_;

    #pragma unroll
    for (int i = 0; i < 3; ++i) {
        int ck = i * 256 + tid;
        int r  = ck >> 3;
        int pc = ck & 7;
        int lc = pc ^ (r & 7);
        int g  = Q0 - 16 + r;
        g = g < 0 ? 0 : (g > L_ - 1 ? L_ - 1 : g);
        async_cp16(qk + (rowbase + g) * QKS_ + DIM_ + h * HDIM_ + lc * 8,
                   Klds + (size_t)ck * 8);
    }

    const int q0w = Q0 + wave * 16;
    const bf16* qptr = qk + (rowbase + q0w + l16) * QKS_ + h * HDIM_ + quad * 8;
    bf16x8 qf0 = *(const bf16x8*)(qptr);
    bf16x8 qf1 = *(const bf16x8*)(qptr + 32);

    int k_base = q0w - 16;
    if (k_base > L_ - 48) k_base = L_ - 48;
    if (k_base < 0) k_base = 0;
    const int rel = k_base - (Q0 - 16);

    __syncthreads();

    f32x4 sacc[3] = {};
    #pragma unroll
    for (int t = 0; t < 3; ++t) {
        int r = rel + t * 16 + l16;
        bf16x8 kf0 = *(const bf16x8*)(Klds + r * 64 + ((quad ^ (r & 7)) * 8));
        bf16x8 kf1 = *(const bf16x8*)(Klds + r * 64 + (((4 + quad) ^ (r & 7)) * 8));
        sacc[t] = __builtin_amdgcn_mfma_f32_16x16x32_bf16(qf0, kf0, sacc[t], 0, 0, 0);
        sacc[t] = __builtin_amdgcn_mfma_f32_16x16x32_bf16(qf1, kf1, sacc[t], 0, 0, 0);
    }

    int offr[4];
    #pragma unroll
    for (int r = 0; r < 4; ++r) {
        int lq = q0w + quad * 4 + r;
        int st = lq - KS_ / 2;
        if (st < 0) st = 0;
        if (st > L_ - KS_) st = L_ - KS_;
        offr[r] = st - k_base;
    }
    float sv[3][4];
    #pragma unroll
    for (int t = 0; t < 3; ++t) {
        int j = t * 16 + l16;
        #pragma unroll
        for (int r = 0; r < 4; ++r) {
            float xv = sacc[t][r] * 0.125f;
            sv[t][r] = (j >= offr[r] && j <= offr[r] + 32) ? xv : -1e30f;
        }
    }

    float mr[4], sum[4];
    #pragma unroll
    for (int r = 0; r < 4; ++r)
        mr[r] = fmaxf(fmaxf(sv[0][r], sv[1][r]), sv[2][r]);
    #pragma unroll
    for (int o = 1; o < 16; o <<= 1)
        #pragma unroll
        for (int r = 0; r < 4; ++r)
            mr[r] = fmaxf(mr[r], __shfl_xor(mr[r], o, 64));
    #pragma unroll
    for (int t = 0; t < 3; ++t)
        #pragma unroll
        for (int r = 0; r < 4; ++r)
            sv[t][r] = __expf(sv[t][r] - mr[r]);
    #pragma unroll
    for (int r = 0; r < 4; ++r)
        sum[r] = sv[0][r] + sv[1][r] + sv[2][r];
    #pragma unroll
    for (int o = 1; o < 16; o <<= 1)
        #pragma unroll
        for (int r = 0; r < 4; ++r)
            sum[r] += __shfl_xor(sum[r], o, 64);
    #pragma unroll
    for (int r = 0; r < 4; ++r) {
        float inv = 1.0f / sum[r];
        #pragma unroll
        for (int t = 0; t < 3; ++t) sv[t][r] *= inv;
    }

    bf16* P = &Plds[wave][0][0];
    {
        int rr = lane >> 2;
        int c0 = 48 + (lane & 3) * 4;
        *(bf16x4*)(&P[rr * 72 + c0]) = (bf16x4){(bf16)0.f, (bf16)0.f, (bf16)0.f, (bf16)0.f};
    }
    #pragma unroll
    for (int t = 0; t < 3; ++t)
        #pragma unroll
        for (int r = 0; r < 4; ++r)
            P[(quad * 4 + r) * 72 + t * 16 + l16] = (bf16)sv[t][r];
    __syncthreads();

    bf16x8 pf0 = *(const bf16x8*)(&P[l16 * 72 + quad * 8]);
    bf16x8 pf1 = *(const bf16x8*)(&P[l16 * 72 + 32 + quad * 8]);

    const bf16* vbase = vT + (size_t)(b * DIM_ + h * HDIM_) * L_;
    int c1 = k_base + quad * 8;
    int c2 = k_base + 32 + quad * 8;
    if (c2 > L_ - 8) c2 = L_ - 8;
    f32x4 o[4] = {};
    #pragma unroll
    for (int t = 0; t < 4; ++t) {
        const bf16* vrow = vbase + (size_t)(t * 16 + l16) * L_;
        bf16x8 vf0 = *(const bf16x8*)(vrow + c1);
        bf16x8 vf1 = *(const bf16x8*)(vrow + c2);
        o[t] = __builtin_amdgcn_mfma_f32_16x16x32_bf16(pf0, vf0, o[t], 0, 0, 0);
        o[t] = __builtin_amdgcn_mfma_f32_16x16x32_bf16(pf1, vf1, o[t], 0, 0, 0);
    }

    bf16* orow = att + (rowbase + q0w) * DIM_ + h * HDIM_;
    #pragma unroll
    for (int t = 0; t < 4; ++t)
        #pragma unroll
        for (int r = 0; r < 4; ++r)
            orow[(size_t)(quad * 4 + r) * DIM_ + t * 16 + l16] = (bf16)o[t][r];
}

extern "C" void kernel_launch(void* const* d_in, const int* in_sizes, int n_in,
                              void* d_out, int out_size, void* d_ws, size_t ws_size,
                              hipStream_t stream) {
    const int n_x  = B_ * L_ * DIM_;       // 4194304
    const int n_wq = 3 * DIM_ * DIM_;      // 786432
    const int n_bq = 3 * DIM_;             // 1536
    const int n_wp = DIM_ * DIM_;          // 262144
    const int n_bp = DIM_;                 // 512

    char* ws = (char*)d_ws;
    bf16* xb  = (bf16*)ws;
    bf16* wqb = xb  + n_x;
    bf16* bqb = wqb + n_wq;
    bf16* wpb = bqb + n_bq;
    bf16* bpb = wpb + n_wp;
    bf16* qk  = bpb + n_bp;                          // 8192 x 1024
    bf16* vT  = qk  + (size_t)8192 * 1024;           // (b, h*d, l)
    bf16* att = vT  + (size_t)B_ * DIM_ * L_;        // 8192 x 512

    float* out = (float*)d_out;
    const int M = B_ * L_;  // 8192

    cvt_all<<<2562, 256, 0, stream>>>(
        (const float*)d_in[0], (const float*)d_in[1], (const float*)d_in[2],
        (const float*)d_in[3], (const float*)d_in[4],
        xb, wqb, bqb, wpb, bpb);

    gemm_qkv<<<dim3(M / 128, (3 * DIM_) / 64), 256, 0, stream>>>(
        xb, wqb, bqb, qk, vT);

    na1d_attn_mfma<<<dim3((B_ * HEADS_ * L_) / 64), 256, 0, stream>>>(qk, vT, att);

    gemm_proj<<<dim3(M / 128, DIM_ / 64), 256, 0, stream>>>(
        att, wpb, bpb, out);
}